// Round 2
// baseline (6947.898 us; speedup 1.0000x reference)
//
#include <hip/hip_runtime.h>
#include <math.h>

#define NB 32
#define NT 128
#define ND 384
#define NH 6
#define NL 6
#define NV 32000
#define NHS 64
#define NBT (NB*NT)      // 4096
#define NFF (4*ND)       // 1536
#define LNEPS 1e-5f

// ---------------- wave helpers ----------------
__device__ __forceinline__ float wave_sum(float v) {
#pragma unroll
    for (int m = 1; m < 64; m <<= 1) v += __shfl_xor(v, m, 64);
    return v;
}
__device__ __forceinline__ float wave_max(float v) {
#pragma unroll
    for (int m = 1; m < 64; m <<= 1) v = fmaxf(v, __shfl_xor(v, m, 64));
    return v;
}

// ---------------- embedding ----------------
__global__ void embed_kernel(const int* __restrict__ tokens,
                             const float* __restrict__ te,
                             const float* __restrict__ pe,
                             float* __restrict__ x) {
    int i = blockIdx.x * 256 + threadIdx.x;
    if (i >= NBT * ND) return;
    int d  = i % ND;
    int bt = i / ND;
    int t  = bt % NT;
    int tok = tokens[bt];
    x[i] = te[(size_t)tok * ND + d] + pe[t * ND + d];
}

// ---------------- repack W{q,k,v}: [L,H,D,HS] -> [L,D,H*HS] ----------------
__global__ void repack_kernel(const float* __restrict__ w, float* __restrict__ wp, int n) {
    int i = blockIdx.x * 256 + threadIdx.x;
    if (i >= n) return;
    int j  = i % ND;          // output col = h*64+e
    int ld = i / ND;
    int d  = ld % ND;
    int l  = ld / ND;
    int h = j >> 6, e = j & 63;
    wp[i] = w[(((size_t)l * NH + h) * ND + d) * NHS + e];
}

// ---------------- layernorm (one block per row) ----------------
__global__ __launch_bounds__(256) void ln_kernel(const float* __restrict__ x,
                                                 const float* __restrict__ g,
                                                 const float* __restrict__ be,
                                                 float* __restrict__ out) {
    __shared__ float red[4];
    int row = blockIdx.x, tid = threadIdx.x;
    const float* xr = x + (size_t)row * ND;
    float v0 = xr[tid];                       // tid < 256 < 384
    bool has1 = (tid + 256) < ND;             // tid < 128
    float v1 = has1 ? xr[tid + 256] : 0.f;

    float s = wave_sum(v0 + v1);
    if ((tid & 63) == 0) red[tid >> 6] = s;
    __syncthreads();
    float mean = (red[0] + red[1] + red[2] + red[3]) * (1.f / ND);
    __syncthreads();

    float d0 = v0 - mean;
    float d1 = has1 ? (v1 - mean) : 0.f;
    float ss = wave_sum(d0 * d0 + d1 * d1);
    if ((tid & 63) == 0) red[tid >> 6] = ss;
    __syncthreads();
    float rstd = rsqrtf((red[0] + red[1] + red[2] + red[3]) * (1.f / ND) + LNEPS);

    float* orow = out + (size_t)row * ND;
    orow[tid] = d0 * rstd * g[tid] + be[tid];
    if (has1) orow[tid + 256] = d1 * rstd * g[tid + 256] + be[tid + 256];
}

// ---------------- generic fp32 GEMM: C(=|+=) A[M,K] @ B[K,N] (+bias)(+relu) ----------------
// flags: 1 = add bias[col], 2 = relu, 4 = residual (C += result)
__global__ __launch_bounds__(256) void gemm_kernel(const float* __restrict__ A,
                                                   const float* __restrict__ Bm,
                                                   const float* __restrict__ bias,
                                                   float* __restrict__ C,
                                                   int M, int N, int K, int flags) {
    __shared__ float As[16][65];
    __shared__ float Bs[16][64];
    int bn = blockIdx.x, bm = blockIdx.y;
    int tid = threadIdx.x;
    int tr = tid >> 4, tc = tid & 15;
    int row0 = bm * 64, col0 = bn * 64;
    float acc[4][4];
#pragma unroll
    for (int i = 0; i < 4; i++)
#pragma unroll
        for (int j = 0; j < 4; j++) acc[i][j] = 0.f;

    for (int k0 = 0; k0 < K; k0 += 16) {
#pragma unroll
        for (int i = tid; i < 1024; i += 256) {   // A tile 64x16
            int r = i >> 4, c = i & 15;
            As[c][r] = A[(size_t)(row0 + r) * K + (k0 + c)];
        }
#pragma unroll
        for (int i = tid; i < 1024; i += 256) {   // B tile 16x64
            int r = i >> 6, c = i & 63;
            Bs[r][c] = Bm[(size_t)(k0 + r) * N + (col0 + c)];
        }
        __syncthreads();
#pragma unroll
        for (int kk = 0; kk < 16; kk++) {
            float a[4], bv[4];
#pragma unroll
            for (int i = 0; i < 4; i++) a[i] = As[kk][tr * 4 + i];
#pragma unroll
            for (int j = 0; j < 4; j++) bv[j] = Bs[kk][tc * 4 + j];
#pragma unroll
            for (int i = 0; i < 4; i++)
#pragma unroll
                for (int j = 0; j < 4; j++) acc[i][j] += a[i] * bv[j];
        }
        __syncthreads();
    }
#pragma unroll
    for (int i = 0; i < 4; i++) {
        size_t r = (size_t)row0 + tr * 4 + i;
#pragma unroll
        for (int j = 0; j < 4; j++) {
            int cc = col0 + tc * 4 + j;
            float t = acc[i][j];
            if (flags & 1) t += bias[cc];
            if (flags & 2) t = fmaxf(t, 0.f);
            float* cp = C + r * (size_t)N + cc;
            if (flags & 4) t += *cp;
            *cp = t;
        }
    }
}

// ---------------- attention: one block per (b,h), 128 threads = 1 query row each ----------------
__global__ __launch_bounds__(128) void attn_kernel(const float* __restrict__ q,
                                                   const float* __restrict__ k,
                                                   const float* __restrict__ v,
                                                   float* __restrict__ o) {
    __shared__ float ks[NT][NHS];
    __shared__ float vs[NT][NHS];
    int bh = blockIdx.x;
    int b = bh / NH, h = bh % NH;
    int tid = threadIdx.x;
    size_t base = (size_t)b * NT * ND + h * NHS;

    for (int i = tid; i < NT * NHS; i += 128) {
        int r = i >> 6, c = i & 63;
        ks[r][c] = k[base + (size_t)r * ND + c];
        vs[r][c] = v[base + (size_t)r * ND + c];
    }
    float qr[NHS];
    {
        const float4* qp = (const float4*)(q + base + (size_t)tid * ND);
#pragma unroll
        for (int e4 = 0; e4 < NHS / 4; ++e4) {
            float4 t = qp[e4];
            qr[e4 * 4 + 0] = t.x; qr[e4 * 4 + 1] = t.y;
            qr[e4 * 4 + 2] = t.z; qr[e4 * 4 + 3] = t.w;
        }
    }
    __syncthreads();

    const float scale = 0.125f;   // HS^-0.5
    // pass 1: row max
    float m = -1e30f;
    for (int j = 0; j <= tid; ++j) {
        float dot = 0.f;
#pragma unroll
        for (int e = 0; e < NHS; e++) dot += qr[e] * ks[j][e];
        m = fmaxf(m, dot * scale);
    }
    // pass 2: exp-weighted accumulation
    float acc[NHS];
#pragma unroll
    for (int e = 0; e < NHS; e++) acc[e] = 0.f;
    float s = 0.f;
    for (int j = 0; j <= tid; ++j) {
        float dot = 0.f;
#pragma unroll
        for (int e = 0; e < NHS; e++) dot += qr[e] * ks[j][e];
        float p = __expf(dot * scale - m);
        s += p;
#pragma unroll
        for (int e = 0; e < NHS; e++) acc[e] += p * vs[j][e];
    }
    float inv = 1.f / s;
    float* op = o + base + (size_t)tid * ND;   // writes o_flat[b, t, h*64+e]
#pragma unroll
    for (int e = 0; e < NHS; e++) op[e] = acc[e] * inv;
}

// ---------------- row softmax over V, in place ----------------
__global__ __launch_bounds__(256) void softmax_kernel(float* __restrict__ out) {
    __shared__ float red[4];
    int row = blockIdx.x, tid = threadIdx.x;
    float* p = out + (size_t)row * NV;
    float m = -1e30f;
    for (int i = tid; i < NV; i += 256) m = fmaxf(m, p[i]);
    m = wave_max(m);
    if ((tid & 63) == 0) red[tid >> 6] = m;
    __syncthreads();
    m = fmaxf(fmaxf(red[0], red[1]), fmaxf(red[2], red[3]));
    __syncthreads();
    float s = 0.f;
    for (int i = tid; i < NV; i += 256) s += __expf(p[i] - m);
    s = wave_sum(s);
    if ((tid & 63) == 0) red[tid >> 6] = s;
    __syncthreads();
    s = red[0] + red[1] + red[2] + red[3];
    float inv = 1.f / s;
    for (int i = tid; i < NV; i += 256) p[i] = __expf(p[i] - m) * inv;
}

// ---------------- launch ----------------
extern "C" void kernel_launch(void* const* d_in, const int* in_sizes, int n_in,
                              void* d_out, int out_size, void* d_ws, size_t ws_size,
                              hipStream_t stream) {
    const int*   tokens  = (const int*)d_in[0];
    const float* tok_emb = (const float*)d_in[1];
    const float* pos_emb = (const float*)d_in[2];
    const float* Wq      = (const float*)d_in[3];
    const float* Wk      = (const float*)d_in[4];
    const float* Wv      = (const float*)d_in[5];
    const float* Wo      = (const float*)d_in[6];
    const float* bo      = (const float*)d_in[7];
    const float* W1      = (const float*)d_in[8];
    const float* b1      = (const float*)d_in[9];
    const float* W2      = (const float*)d_in[10];
    const float* b2      = (const float*)d_in[11];
    const float* g1      = (const float*)d_in[12];
    const float* be1     = (const float*)d_in[13];
    const float* g2      = (const float*)d_in[14];
    const float* be2     = (const float*)d_in[15];
    const float* gf      = (const float*)d_in[16];
    const float* bef     = (const float*)d_in[17];
    const float* Wout    = (const float*)d_in[18];
    const float* bout    = (const float*)d_in[19];
    float* out = (float*)d_out;

    // scratch layout (floats). Everything except hbuf is dead before the logits
    // GEMM, so it can live in d_out (131M floats) when d_ws is small. hbuf is
    // read DURING the logits GEMM -> must not alias d_out.
    const size_t SZ_XD   = (size_t)NBT * ND;      // 1572864
    const size_t SZ_U    = (size_t)NBT * NFF;     // 6291456
    const size_t SZ_W    = (size_t)NL * ND * ND;  // 884736
    const size_t need_all = (5 * SZ_XD + SZ_U + 3 * SZ_W + SZ_XD) * sizeof(float);

    float* base;
    float* hbuf;
    if (ws_size >= need_all) {
        base = (float*)d_ws;
        hbuf = base + (5 * SZ_XD + SZ_U + 3 * SZ_W);
    } else {
        base = out;               // use output buffer as scratch
        hbuf = (float*)d_ws;      // needs ~6.3 MB of workspace
    }
    float* xbuf = base;
    float* qbuf = xbuf + SZ_XD;
    float* kbuf = qbuf + SZ_XD;
    float* vbuf = kbuf + SZ_XD;
    float* obuf = vbuf + SZ_XD;
    float* ubuf = obuf + SZ_XD;
    float* wqp  = ubuf + SZ_U;
    float* wkp  = wqp + SZ_W;
    float* wvp  = wkp + SZ_W;

    int n = NL * ND * ND;
    repack_kernel<<<(n + 255) / 256, 256, 0, stream>>>(Wq, wqp, n);
    repack_kernel<<<(n + 255) / 256, 256, 0, stream>>>(Wk, wkp, n);
    repack_kernel<<<(n + 255) / 256, 256, 0, stream>>>(Wv, wvp, n);
    n = NBT * ND;
    embed_kernel<<<(n + 255) / 256, 256, 0, stream>>>(tokens, tok_emb, pos_emb, xbuf);

    dim3 gsmall(ND / 64, NBT / 64);   // (6, 64)
    dim3 gff(NFF / 64, NBT / 64);     // (24, 64)
    dim3 gout(NV / 64, NBT / 64);     // (500, 64)

    for (int l = 0; l < NL; l++) {
        ln_kernel<<<NBT, 256, 0, stream>>>(xbuf, g1 + l * ND, be1 + l * ND, hbuf);
        gemm_kernel<<<gsmall, 256, 0, stream>>>(hbuf, wqp + (size_t)l * ND * ND, nullptr, qbuf, NBT, ND, ND, 0);
        gemm_kernel<<<gsmall, 256, 0, stream>>>(hbuf, wkp + (size_t)l * ND * ND, nullptr, kbuf, NBT, ND, ND, 0);
        gemm_kernel<<<gsmall, 256, 0, stream>>>(hbuf, wvp + (size_t)l * ND * ND, nullptr, vbuf, NBT, ND, ND, 0);
        attn_kernel<<<NB * NH, 128, 0, stream>>>(qbuf, kbuf, vbuf, obuf);
        gemm_kernel<<<gsmall, 256, 0, stream>>>(obuf, Wo + (size_t)l * ND * ND, bo + l * ND, xbuf, NBT, ND, ND, 1 | 4);
        ln_kernel<<<NBT, 256, 0, stream>>>(xbuf, g2 + l * ND, be2 + l * ND, hbuf);
        gemm_kernel<<<gff, 256, 0, stream>>>(hbuf, W1 + (size_t)l * ND * NFF, b1 + l * NFF, ubuf, NBT, NFF, ND, 1 | 2);
        gemm_kernel<<<gsmall, 256, 0, stream>>>(ubuf, W2 + (size_t)l * NFF * ND, b2 + l * ND, xbuf, NBT, ND, NFF, 1 | 4);
    }
    ln_kernel<<<NBT, 256, 0, stream>>>(xbuf, gf, bef, hbuf);
    gemm_kernel<<<gout, 256, 0, stream>>>(hbuf, Wout, bout, out, NBT, NV, ND, 1);
    softmax_kernel<<<NBT, 256, 0, stream>>>(out);
}

// Round 5
// 2731.462 us; speedup vs baseline: 2.5437x; 2.5437x over previous
//
#include <hip/hip_runtime.h>
#include <math.h>

#define NB 32
#define NT 128
#define ND 384
#define NH 6
#define NL 6
#define NV 32000
#define NHS 64
#define NBT (NB*NT)      // 4096
#define NFF (4*ND)       // 1536
#define NQKV (3*ND)      // 1152
#define LNEPS 1e-5f

typedef unsigned short u16;
typedef unsigned int   u32;
typedef __attribute__((ext_vector_type(8))) short bf16x8;
typedef __attribute__((ext_vector_type(4))) float f32x4;

#define FLAG_BIAS 1
#define FLAG_RELU 2
#define FLAG_RESID 4
#define FLAG_BF16OUT 8

__device__ __forceinline__ float bf2f(u16 h) { return __uint_as_float((u32)h << 16); }
__device__ __forceinline__ u16 f2bf(float f) {
    u32 u = __float_as_uint(f);
    u32 r = u + 0x7fffu + ((u >> 16) & 1u);
    return (u16)(r >> 16);
}

// ---------------- wave helpers ----------------
__device__ __forceinline__ float wave_sum(float v) {
#pragma unroll
    for (int m = 1; m < 64; m <<= 1) v += __shfl_xor(v, m, 64);
    return v;
}
__device__ __forceinline__ float wave_max(float v) {
#pragma unroll
    for (int m = 1; m < 64; m <<= 1) v = fmaxf(v, __shfl_xor(v, m, 64));
    return v;
}

// ---------------- embedding ----------------
__global__ void embed_kernel(const int* __restrict__ tokens,
                             const float* __restrict__ te,
                             const float* __restrict__ pe,
                             float* __restrict__ x) {
    int i = blockIdx.x * 256 + threadIdx.x;
    if (i >= NBT * ND) return;
    int d  = i % ND;
    int bt = i / ND;
    int t  = bt % NT;
    int tok = tokens[bt];
    x[i] = te[(size_t)tok * ND + d] + pe[t * ND + d];
}

// ---------------- transpose + fp32->bf16 convert ----------------
// in fp32 [z][R][C] -> out bf16 [z][C][R]; z decomposed (l,h) when zH>1 for QKV packing
__global__ __launch_bounds__(256) void transpose_cvt_kernel(
    const float* __restrict__ in, u16* __restrict__ out,
    int R, int C, long in_z_stride, long out_z_stride, int zH, long out_h_stride)
{
    __shared__ float tile[32][33];
    int z = blockIdx.z;
    long in_off = (long)z * in_z_stride;
    long out_off;
    if (zH > 1) { int l = z / zH, h = z % zH;
        out_off = (long)l * out_z_stride + (long)h * out_h_stride; }
    else out_off = (long)z * out_z_stride;
    int r0 = blockIdx.y * 32, c0 = blockIdx.x * 32;
    int tx = threadIdx.x & 31, ty = threadIdx.x >> 5;  // 32x8
#pragma unroll
    for (int i = 0; i < 32; i += 8)
        tile[ty + i][tx] = in[in_off + (size_t)(r0 + ty + i) * C + c0 + tx];
    __syncthreads();
#pragma unroll
    for (int i = 0; i < 32; i += 8)
        out[out_off + (size_t)(c0 + ty + i) * R + r0 + tx] = f2bf(tile[tx][ty + i]);
}

// ---------------- layernorm (one block per row); out fp32 or bf16 ----------------
template <int BF16OUT>
__global__ __launch_bounds__(256) void ln_kernel(const float* __restrict__ x,
                                                 const float* __restrict__ g,
                                                 const float* __restrict__ be,
                                                 float* __restrict__ outf,
                                                 u16* __restrict__ outb) {
    __shared__ float red[4];
    int row = blockIdx.x, tid = threadIdx.x;
    const float* xr = x + (size_t)row * ND;
    float v0 = xr[tid];
    bool has1 = (tid + 256) < ND;
    float v1 = has1 ? xr[tid + 256] : 0.f;

    float s = wave_sum(v0 + v1);
    if ((tid & 63) == 0) red[tid >> 6] = s;
    __syncthreads();
    float mean = (red[0] + red[1] + red[2] + red[3]) * (1.f / ND);
    __syncthreads();

    float d0 = v0 - mean;
    float d1 = has1 ? (v1 - mean) : 0.f;
    float ss = wave_sum(d0 * d0 + d1 * d1);
    if ((tid & 63) == 0) red[tid >> 6] = ss;
    __syncthreads();
    float rstd = rsqrtf((red[0] + red[1] + red[2] + red[3]) * (1.f / ND) + LNEPS);

    float o0 = d0 * rstd * g[tid] + be[tid];
    if (BF16OUT) {
        u16* orow = outb + (size_t)row * ND;
        orow[tid] = f2bf(o0);
        if (has1) orow[tid + 256] = f2bf(d1 * rstd * g[tid + 256] + be[tid + 256]);
    } else {
        float* orow = outf + (size_t)row * ND;
        orow[tid] = o0;
        if (has1) orow[tid + 256] = d1 * rstd * g[tid + 256] + be[tid + 256];
    }
}

// ---------------- bf16 MFMA GEMM: C = A[M,K] @ Bt[N,K]^T (+bias)(+relu)(+resid) ----------------
// 128x128 tile, BK=32, 256 threads = 4 waves in 2x2, each wave 64x64 via 4x4 mfma_16x16x32
#define BM 128
#define BN 128
#define BK 32
#define KPAD 40   // padded k-stride (elements); 80B row stride -> balanced banks

__global__ __launch_bounds__(256) void gemm_bf16_kernel(
    const u16* __restrict__ A,    // [M][K] bf16
    const u16* __restrict__ Bt,   // [N][K] bf16 (pre-transposed)
    const float* __restrict__ bias,
    float* __restrict__ Cf,       // fp32 out / residual source
    u16* __restrict__ Cb,         // bf16 out
    int M, int N, int K, int flags)
{
    __shared__ u16 As[BM * KPAD];
    __shared__ u16 Bs[BN * KPAD];
    int tid = threadIdx.x;
    int bn = blockIdx.x, bm = blockIdx.y;
    int row0 = bm * BM, col0 = bn * BN;
    int wave = tid >> 6, lane = tid & 63;
    int wr = wave >> 1, wc = wave & 1;
    int lrow = lane & 15;
    int kgrp = lane >> 4;

    f32x4 acc[4][4];
#pragma unroll
    for (int i = 0; i < 4; i++)
#pragma unroll
        for (int j = 0; j < 4; j++) acc[i][j] = (f32x4){0.f, 0.f, 0.f, 0.f};

    // staging: 512 16B-chunks per tile (128 rows x 4 k-segments); 2 chunks/thread
    int c0 = tid * 2;
    int sr0 = c0 >> 2, sk0 = (c0 & 3) * 8;
    int c1 = c0 + 1;
    int sr1 = c1 >> 2, sk1 = (c1 & 3) * 8;

    const size_t arow0 = (size_t)(row0 + sr0) * K;
    const size_t arow1 = (size_t)(row0 + sr1) * K;
    const size_t brow0 = (size_t)(col0 + sr0) * K;
    const size_t brow1 = (size_t)(col0 + sr1) * K;

    for (int k0 = 0; k0 < K; k0 += BK) {
        bf16x8 a0 = *(const bf16x8*)&A[arow0 + k0 + sk0];
        bf16x8 a1 = *(const bf16x8*)&A[arow1 + k0 + sk1];
        bf16x8 b0 = *(const bf16x8*)&Bt[brow0 + k0 + sk0];
        bf16x8 b1 = *(const bf16x8*)&Bt[brow1 + k0 + sk1];
        __syncthreads();   // previous iteration's reads complete
        *(bf16x8*)&As[sr0 * KPAD + sk0] = a0;
        *(bf16x8*)&As[sr1 * KPAD + sk1] = a1;
        *(bf16x8*)&Bs[sr0 * KPAD + sk0] = b0;
        *(bf16x8*)&Bs[sr1 * KPAD + sk1] = b1;
        __syncthreads();

        bf16x8 af[4], bfr[4];
#pragma unroll
        for (int mi = 0; mi < 4; mi++)
            af[mi] = *(const bf16x8*)&As[(wr * 64 + mi * 16 + lrow) * KPAD + kgrp * 8];
#pragma unroll
        for (int ni = 0; ni < 4; ni++)
            bfr[ni] = *(const bf16x8*)&Bs[(wc * 64 + ni * 16 + lrow) * KPAD + kgrp * 8];
#pragma unroll
        for (int mi = 0; mi < 4; mi++)
#pragma unroll
            for (int ni = 0; ni < 4; ni++)
                acc[mi][ni] = __builtin_amdgcn_mfma_f32_16x16x32_bf16(
                    af[mi], bfr[ni], acc[mi][ni], 0, 0, 0);
    }

    // epilogue: C/D layout col=lane&15, row=(lane>>4)*4+j
#pragma unroll
    for (int mi = 0; mi < 4; mi++) {
#pragma unroll
        for (int ni = 0; ni < 4; ni++) {
            int c = col0 + wc * 64 + ni * 16 + lrow;
            int rb = row0 + wr * 64 + mi * 16 + kgrp * 4;
#pragma unroll
            for (int j = 0; j < 4; j++) {
                size_t idx = (size_t)(rb + j) * N + c;
                float v = acc[mi][ni][j];
                if (flags & FLAG_BIAS) v += bias[c];
                if (flags & FLAG_RELU) v = fmaxf(v, 0.f);
                if (flags & FLAG_RESID) v += Cf[idx];
                if (flags & FLAG_BF16OUT) Cb[idx] = f2bf(v);
                else Cf[idx] = v;
            }
        }
    }
}

// ---------------- fp32 fallback GEMM (path C logits only) ----------------
__global__ __launch_bounds__(256) void gemm_f32_kernel(const float* __restrict__ A,
                                                       const float* __restrict__ Bm,
                                                       const float* __restrict__ bias,
                                                       float* __restrict__ C,
                                                       int M, int N, int K, int flags) {
    __shared__ float Asl[16][65];
    __shared__ float Bsl[16][64];
    int bn = blockIdx.x, bm = blockIdx.y;
    int tid = threadIdx.x;
    int tr = tid >> 4, tc = tid & 15;
    int row0 = bm * 64, col0 = bn * 64;
    float acc[4][4];
#pragma unroll
    for (int i = 0; i < 4; i++)
#pragma unroll
        for (int j = 0; j < 4; j++) acc[i][j] = 0.f;

    for (int k0 = 0; k0 < K; k0 += 16) {
#pragma unroll
        for (int i = tid; i < 1024; i += 256) {
            int r = i >> 4, c = i & 15;
            Asl[c][r] = A[(size_t)(row0 + r) * K + (k0 + c)];
        }
#pragma unroll
        for (int i = tid; i < 1024; i += 256) {
            int r = i >> 6, c = i & 63;
            Bsl[r][c] = Bm[(size_t)(k0 + r) * N + (col0 + c)];
        }
        __syncthreads();
#pragma unroll
        for (int kk = 0; kk < 16; kk++) {
            float a[4], bv[4];
#pragma unroll
            for (int i = 0; i < 4; i++) a[i] = Asl[kk][tr * 4 + i];
#pragma unroll
            for (int j = 0; j < 4; j++) bv[j] = Bsl[kk][tc * 4 + j];
#pragma unroll
            for (int i = 0; i < 4; i++)
#pragma unroll
                for (int j = 0; j < 4; j++) acc[i][j] += a[i] * bv[j];
        }
        __syncthreads();
    }
#pragma unroll
    for (int i = 0; i < 4; i++) {
        size_t r = (size_t)row0 + tr * 4 + i;
#pragma unroll
        for (int j = 0; j < 4; j++) {
            int cc = col0 + tc * 4 + j;
            float t = acc[i][j];
            if (flags & 1) t += bias[cc];
            C[r * (size_t)N + cc] = t;
        }
    }
}

// ---------------- attention: block per (b,h), bf16 I/O, fp32 math ----------------
__global__ __launch_bounds__(128) void attn_kernel(const u16* __restrict__ qkv,
                                                   u16* __restrict__ o) {
    __shared__ float ks[NT][NHS];
    __shared__ float vs[NT][NHS];
    int bh = blockIdx.x;
    int b = bh / NH, h = bh % NH;
    int tid = threadIdx.x;
    size_t row0 = (size_t)b * NT;

    for (int i = tid; i < NT * (NHS / 8); i += 128) {
        int r = i >> 3, c8 = (i & 7) * 8;
        bf16x8 kv = *(const bf16x8*)&qkv[(row0 + r) * NQKV + ND + h * NHS + c8];
        bf16x8 vv = *(const bf16x8*)&qkv[(row0 + r) * NQKV + 2 * ND + h * NHS + c8];
#pragma unroll
        for (int j = 0; j < 8; j++) {
            ks[r][c8 + j] = bf2f((u16)kv[j]);
            vs[r][c8 + j] = bf2f((u16)vv[j]);
        }
    }
    float qr[NHS];
    {
        const u16* qp = &qkv[(row0 + tid) * NQKV + h * NHS];
#pragma unroll
        for (int e8 = 0; e8 < 8; e8++) {
            bf16x8 qv = *(const bf16x8*)(qp + e8 * 8);
#pragma unroll
            for (int j = 0; j < 8; j++) qr[e8 * 8 + j] = bf2f((u16)qv[j]);
        }
    }
    __syncthreads();

    const float scale = 0.125f;
    float m = -1e30f;
    for (int j = 0; j <= tid; ++j) {
        float dot = 0.f;
#pragma unroll
        for (int e = 0; e < NHS; e++) dot += qr[e] * ks[j][e];
        m = fmaxf(m, dot * scale);
    }
    float acc[NHS];
#pragma unroll
    for (int e = 0; e < NHS; e++) acc[e] = 0.f;
    float s = 0.f;
    for (int j = 0; j <= tid; ++j) {
        float dot = 0.f;
#pragma unroll
        for (int e = 0; e < NHS; e++) dot += qr[e] * ks[j][e];
        float p = __expf(dot * scale - m);
        s += p;
#pragma unroll
        for (int e = 0; e < NHS; e++) acc[e] += p * vs[j][e];
    }
    float inv = 1.f / s;
    u16* op = o + (row0 + tid) * ND + h * NHS;
#pragma unroll
    for (int e = 0; e < NHS; e++) op[e] = f2bf(acc[e] * inv);
}

// ---------------- row softmax over V: 1 read + 1 write, values in registers ----------------
__global__ __launch_bounds__(1024) void softmax_kernel(float* __restrict__ out) {
    __shared__ float red[16];
    int row = blockIdx.x, tid = threadIdx.x;
    float* p = out + (size_t)row * NV;
    const int nch = NV / 4;     // 8000 float4 chunks
    float4 v[8];
    float m = -1e30f;
#pragma unroll
    for (int i = 0; i < 8; i++) {
        int c = tid + i * 1024;
        if (c < nch) {
            v[i] = ((const float4*)p)[c];
            m = fmaxf(m, fmaxf(fmaxf(v[i].x, v[i].y), fmaxf(v[i].z, v[i].w)));
        }
    }
    m = wave_max(m);
    if ((tid & 63) == 0) red[tid >> 6] = m;
    __syncthreads();
    float mm = red[0];
#pragma unroll
    for (int i = 1; i < 16; i++) mm = fmaxf(mm, red[i]);
    __syncthreads();
    float s = 0.f;
#pragma unroll
    for (int i = 0; i < 8; i++) {
        int c = tid + i * 1024;
        if (c < nch) {
            v[i].x = __expf(v[i].x - mm); v[i].y = __expf(v[i].y - mm);
            v[i].z = __expf(v[i].z - mm); v[i].w = __expf(v[i].w - mm);
            s += v[i].x + v[i].y + v[i].z + v[i].w;
        }
    }
    s = wave_sum(s);
    if ((tid & 63) == 0) red[tid >> 6] = s;
    __syncthreads();
    float ss = 0.f;
#pragma unroll
    for (int i = 0; i < 16; i++) ss += red[i];
    float inv = 1.f / ss;
#pragma unroll
    for (int i = 0; i < 8; i++) {
        int c = tid + i * 1024;
        if (c < nch) {
            v[i].x *= inv; v[i].y *= inv; v[i].z *= inv; v[i].w *= inv;
            ((float4*)p)[c] = v[i];
        }
    }
}

// ---------------- launch ----------------
extern "C" void kernel_launch(void* const* d_in, const int* in_sizes, int n_in,
                              void* d_out, int out_size, void* d_ws, size_t ws_size,
                              hipStream_t stream) {
    const int*   tokens  = (const int*)d_in[0];
    const float* tok_emb = (const float*)d_in[1];
    const float* pos_emb = (const float*)d_in[2];
    const float* Wq      = (const float*)d_in[3];
    const float* Wk      = (const float*)d_in[4];
    const float* Wv      = (const float*)d_in[5];
    const float* Wo      = (const float*)d_in[6];
    const float* bo      = (const float*)d_in[7];
    const float* W1      = (const float*)d_in[8];
    const float* b1      = (const float*)d_in[9];
    const float* W2      = (const float*)d_in[10];
    const float* b2      = (const float*)d_in[11];
    const float* g1      = (const float*)d_in[12];
    const float* be1     = (const float*)d_in[13];
    const float* g2      = (const float*)d_in[14];
    const float* be2     = (const float*)d_in[15];
    const float* gf      = (const float*)d_in[16];
    const float* bef     = (const float*)d_in[17];
    const float* Wout    = (const float*)d_in[18];
    const float* bout    = (const float*)d_in[19];
    float* out = (float*)d_out;

    // buffer sizes (bytes)
    const size_t S_hb   = (size_t)NBT * ND * 2;          // LN out bf16
    const size_t S_wout = (size_t)NV * ND * 2;           // Wout^T bf16
    const size_t S_x    = (size_t)NBT * ND * 4;          // residual fp32
    const size_t S_qkv  = (size_t)NBT * NQKV * 2;
    const size_t S_o    = (size_t)NBT * ND * 2;
    const size_t S_u    = (size_t)NBT * NFF * 2;
    const size_t S_wqkv = (size_t)NL * NQKV * ND * 2;
    const size_t S_wo   = (size_t)NL * ND * ND * 2;
    const size_t S_w1   = (size_t)NL * ND * NFF * 2;
    const size_t S_w2   = (size_t)NL * NFF * ND * 2;
    const size_t S_hf   = (size_t)NBT * ND * 4;          // LN out fp32 (path C)
    auto al = [](size_t x) { return (x + 255) & ~(size_t)255; };

    const size_t needA = al(S_hb) + al(S_wout) + al(S_x) + al(S_qkv) + al(S_o) +
                         al(S_u) + al(S_wqkv) + al(S_wo) + al(S_w1) + al(S_w2);
    const size_t needB = al(S_hb) + al(S_wout);

    char* wsb  = (char*)d_ws;
    char* outb = (char*)d_out;
    bool fp32_logits = false;

    u16 *hb, *woutt, *qkvb, *ob, *ub, *wqkvt, *wot, *w1t, *w2t;
    float *xbuf, *hf = nullptr;

    if (ws_size >= needA) {
        char* p = wsb;
        hb    = (u16*)p; p += al(S_hb);
        woutt = (u16*)p; p += al(S_wout);
        xbuf  = (float*)p; p += al(S_x);
        qkvb  = (u16*)p; p += al(S_qkv);
        ob    = (u16*)p; p += al(S_o);
        ub    = (u16*)p; p += al(S_u);
        wqkvt = (u16*)p; p += al(S_wqkv);
        wot   = (u16*)p; p += al(S_wo);
        w1t   = (u16*)p; p += al(S_w1);
        w2t   = (u16*)p; p += al(S_w2);
    } else if (ws_size >= needB) {
        char* p = wsb;
        hb    = (u16*)p; p += al(S_hb);
        woutt = (u16*)p; p += al(S_wout);
        char* q = outb;          // dead before logits GEMM
        xbuf  = (float*)q; q += al(S_x);
        qkvb  = (u16*)q; q += al(S_qkv);
        ob    = (u16*)q; q += al(S_o);
        ub    = (u16*)q; q += al(S_u);
        wqkvt = (u16*)q; q += al(S_wqkv);
        wot   = (u16*)q; q += al(S_wo);
        w1t   = (u16*)q; q += al(S_w1);
        w2t   = (u16*)q; q += al(S_w2);
    } else {
        // path C: fp32 logits GEMM; only fp32 LN out lives in ws (proven >= 6.3MB)
        fp32_logits = true;
        hf = (float*)wsb;
        woutt = nullptr;
        char* q = outb;
        hb    = (u16*)q; q += al(S_hb);
        xbuf  = (float*)q; q += al(S_x);
        qkvb  = (u16*)q; q += al(S_qkv);
        ob    = (u16*)q; q += al(S_o);
        ub    = (u16*)q; q += al(S_u);
        wqkvt = (u16*)q; q += al(S_wqkv);
        wot   = (u16*)q; q += al(S_wo);
        w1t   = (u16*)q; q += al(S_w1);
        w2t   = (u16*)q; q += al(S_w2);
    }

    // ---- one-time weight transpose/convert ----
    {
        const float* Wsides[3] = {Wq, Wk, Wv};
        for (int s = 0; s < 3; s++)
            transpose_cvt_kernel<<<dim3(NHS / 32, ND / 32, NL * NH), 256, 0, stream>>>(
                Wsides[s], wqkvt + (size_t)s * ND * ND, ND, NHS,
                (long)ND * NHS, (long)NQKV * ND, NH, (long)NHS * ND);
        transpose_cvt_kernel<<<dim3(ND / 32, ND / 32, NL), 256, 0, stream>>>(
            Wo, wot, ND, ND, (long)ND * ND, (long)ND * ND, 1, 0);
        transpose_cvt_kernel<<<dim3(NFF / 32, ND / 32, NL), 256, 0, stream>>>(
            W1, w1t, ND, NFF, (long)ND * NFF, (long)NFF * ND, 1, 0);
        transpose_cvt_kernel<<<dim3(ND / 32, NFF / 32, NL), 256, 0, stream>>>(
            W2, w2t, NFF, ND, (long)NFF * ND, (long)ND * NFF, 1, 0);
        if (!fp32_logits)
            transpose_cvt_kernel<<<dim3(NV / 32, ND / 32, 1), 256, 0, stream>>>(
                Wout, woutt, ND, NV, 0, 0, 1, 0);
    }

    int n = NBT * ND;
    embed_kernel<<<(n + 255) / 256, 256, 0, stream>>>(tokens, tok_emb, pos_emb, xbuf);

    dim3 g_qkv(NQKV / BN, NBT / BM);   // (9, 32)
    dim3 g_d(ND / BN, NBT / BM);       // (3, 32)
    dim3 g_ff(NFF / BN, NBT / BM);     // (12, 32)
    dim3 g_out(NV / BN, NBT / BM);     // (250, 32)

    for (int l = 0; l < NL; l++) {
        ln_kernel<1><<<NBT, 256, 0, stream>>>(xbuf, g1 + l * ND, be1 + l * ND, nullptr, hb);
        gemm_bf16_kernel<<<g_qkv, 256, 0, stream>>>(hb, wqkvt + (size_t)l * NQKV * ND,
            nullptr, nullptr, qkvb, NBT, NQKV, ND, FLAG_BF16OUT);
        attn_kernel<<<NB * NH, 128, 0, stream>>>(qkvb, ob);
        gemm_bf16_kernel<<<g_d, 256, 0, stream>>>(ob, wot + (size_t)l * ND * ND,
            bo + l * ND, xbuf, nullptr, NBT, ND, ND, FLAG_BIAS | FLAG_RESID);
        ln_kernel<1><<<NBT, 256, 0, stream>>>(xbuf, g2 + l * ND, be2 + l * ND, nullptr, hb);
        gemm_bf16_kernel<<<g_ff, 256, 0, stream>>>(hb, w1t + (size_t)l * ND * NFF,
            b1 + l * NFF, nullptr, ub, NBT, NFF, ND, FLAG_BIAS | FLAG_RELU | FLAG_BF16OUT);
        gemm_bf16_kernel<<<g_d, 256, 0, stream>>>(ub, w2t + (size_t)l * NFF * ND,
            b2 + l * ND, xbuf, nullptr, NBT, ND, NFF, FLAG_BIAS | FLAG_RESID);
    }

    if (!fp32_logits) {
        ln_kernel<1><<<NBT, 256, 0, stream>>>(xbuf, gf, bef, nullptr, hb);
        gemm_bf16_kernel<<<g_out, 256, 0, stream>>>(hb, woutt, bout, out, nullptr,
            NBT, NV, ND, FLAG_BIAS);
    } else {
        ln_kernel<0><<<NBT, 256, 0, stream>>>(xbuf, gf, bef, hf, nullptr);
        gemm_f32_kernel<<<dim3(NV / 64, NBT / 64), 256, 0, stream>>>(
            hf, Wout, bout, out, NBT, NV, ND, 1);
    }
    softmax_kernel<<<NBT, 1024, 0, stream>>>(out);
}